// Round 1
// baseline (266.066 us; speedup 1.0000x reference)
//
#include <hip/hip_runtime.h>

// Broadcast lane `l`'s value of v to all lanes via v_readlane (SGPR result).
__device__ __forceinline__ float bcast(float v, int l) {
    return __int_as_float(__builtin_amdgcn_readlane(__float_as_int(v), l));
}

// ---------------------------------------------------------------------------
// Stage 1: per-batch GD solve.  x_{k+1} = x_k + 2a*(Hty - H^T(H x_k))
// One wave per batch. Lane r holds row r (hrow) and column r (hcol) of H.
// ---------------------------------------------------------------------------
__global__ __launch_bounds__(256) void gd_solve(
    const float* __restrict__ y,
    const float* __restrict__ H,
    const float* __restrict__ x0,
    const float* __restrict__ step_size,
    const int*   __restrict__ iters,
    float* __restrict__ z_out)
{
    const int lane = threadIdx.x & 63;
    const int wave = threadIdx.x >> 6;
    const int b = blockIdx.x * 4 + wave;
    const float* __restrict__ Hb = H + (size_t)b * 4096;

    // Coalesced column load first (streams the 16KB tile from HBM):
    // hcol[r] = H[b][r][lane]   (lane owns column t=lane)
    float hcol[64];
    #pragma unroll
    for (int r = 0; r < 64; ++r) hcol[r] = Hb[r * 64 + lane];

    // Row load second (tile now in L1/L2/LLC):
    // hrow[t] = H[b][lane][t]   (lane owns row r=lane)
    float hrow[64];
    #pragma unroll
    for (int j = 0; j < 16; ++j) {
        const float4 t4 = *reinterpret_cast<const float4*>(Hb + lane * 64 + j * 4);
        hrow[4*j+0] = t4.x; hrow[4*j+1] = t4.y;
        hrow[4*j+2] = t4.z; hrow[4*j+3] = t4.w;
    }

    const float yv = y[b * 64 + lane];
    const float ts = 2.0f * step_size[0];
    const int n_it = iters[0];

    // Hty[lane] = sum_r H[r][lane] * y[r]
    float h0 = 0.f, h1 = 0.f, h2 = 0.f, h3 = 0.f;
    #pragma unroll
    for (int r = 0; r < 64; r += 4) {
        h0 = fmaf(hcol[r+0], bcast(yv, r+0), h0);
        h1 = fmaf(hcol[r+1], bcast(yv, r+1), h1);
        h2 = fmaf(hcol[r+2], bcast(yv, r+2), h2);
        h3 = fmaf(hcol[r+3], bcast(yv, r+3), h3);
    }
    const float hty = (h0 + h1) + (h2 + h3);

    float xv = x0[b * 64 + lane];
    for (int it = 0; it < n_it; ++it) {
        // v[lane] = sum_t H[lane][t] * x[t]
        float a0 = 0.f, a1 = 0.f, a2 = 0.f, a3 = 0.f;
        #pragma unroll
        for (int t = 0; t < 64; t += 4) {
            a0 = fmaf(hrow[t+0], bcast(xv, t+0), a0);
            a1 = fmaf(hrow[t+1], bcast(xv, t+1), a1);
            a2 = fmaf(hrow[t+2], bcast(xv, t+2), a2);
            a3 = fmaf(hrow[t+3], bcast(xv, t+3), a3);
        }
        const float v = (a0 + a1) + (a2 + a3);
        // w[lane] = sum_r H[r][lane] * v[r]
        float w0 = 0.f, w1 = 0.f, w2 = 0.f, w3 = 0.f;
        #pragma unroll
        for (int r = 0; r < 64; r += 4) {
            w0 = fmaf(hcol[r+0], bcast(v, r+0), w0);
            w1 = fmaf(hcol[r+1], bcast(v, r+1), w1);
            w2 = fmaf(hcol[r+2], bcast(v, r+2), w2);
            w3 = fmaf(hcol[r+3], bcast(v, r+3), w3);
        }
        const float w = (w0 + w1) + (w2 + w3);
        xv = fmaf(ts, hty - w, xv);
    }
    z_out[b * 64 + lane] = xv;
}

// ---------------------------------------------------------------------------
// Stage 2: h_new[b][j] = relu(z[b]·W_ih[j] + b_ih[j] + h[b]·W_hh[j] + b_hh[j])
// Thread j holds W rows in VGPRs; z/h loads are wave-uniform -> s_load.
// ---------------------------------------------------------------------------
#define NB1 16
__global__ __launch_bounds__(256) void rnn_cell(
    const float* __restrict__ z,
    const float* __restrict__ h,
    const float* __restrict__ W_ih,
    const float* __restrict__ W_hh,
    const float* __restrict__ b_ih,
    const float* __restrict__ b_hh,
    float* __restrict__ h_new)
{
    const int j  = threadIdx.x;            // 0..255 output feature
    const int b0 = blockIdx.x * NB1;

    float wih[64];
    #pragma unroll
    for (int k = 0; k < 16; ++k) {
        const float4 t4 = *reinterpret_cast<const float4*>(W_ih + j * 64 + k * 4);
        wih[4*k+0] = t4.x; wih[4*k+1] = t4.y; wih[4*k+2] = t4.z; wih[4*k+3] = t4.w;
    }
    const float bias = b_ih[j] + b_hh[j];

    float acc[NB1];
    #pragma unroll
    for (int b = 0; b < NB1; b += 2) {
        const float* zb0 = z + (size_t)(b0 + b) * 64;   // wave-uniform
        const float* zb1 = zb0 + 64;
        float a0 = bias, a1 = bias;
        #pragma unroll
        for (int k = 0; k < 64; ++k) {
            a0 = fmaf(wih[k], zb0[k], a0);
            a1 = fmaf(wih[k], zb1[k], a1);
        }
        acc[b] = a0; acc[b+1] = a1;
    }

    for (int c = 0; c < 4; ++c) {          // W_hh K-chunks of 64
        float whh[64];
        #pragma unroll
        for (int k = 0; k < 16; ++k) {
            const float4 t4 = *reinterpret_cast<const float4*>(W_hh + j * 256 + c * 64 + k * 4);
            whh[4*k+0] = t4.x; whh[4*k+1] = t4.y; whh[4*k+2] = t4.z; whh[4*k+3] = t4.w;
        }
        #pragma unroll
        for (int b = 0; b < NB1; b += 2) {
            const float* hb0 = h + (size_t)(b0 + b) * 256 + c * 64;  // wave-uniform
            const float* hb1 = hb0 + 256;
            float a0 = acc[b], a1 = acc[b+1];
            #pragma unroll
            for (int k = 0; k < 64; ++k) {
                a0 = fmaf(whh[k], hb0[k], a0);
                a1 = fmaf(whh[k], hb1[k], a1);
            }
            acc[b] = a0; acc[b+1] = a1;
        }
    }

    #pragma unroll
    for (int b = 0; b < NB1; ++b)
        h_new[(size_t)(b0 + b) * 256 + j] = fmaxf(acc[b], 0.0f);
}

// ---------------------------------------------------------------------------
// Stage 3: x_out[b][t] = h_new[b]·w_x[t] + b_x[t]
// lane = t, wave (sub) = K-chunk of 64; LDS reduce across 4 waves.
// ---------------------------------------------------------------------------
#define NB2 16
__global__ __launch_bounds__(256) void out_proj(
    const float* __restrict__ h_new,
    const float* __restrict__ w_x,
    const float* __restrict__ b_x,
    float* __restrict__ x_out)
{
    const int lane = threadIdx.x & 63;
    const int sub  = threadIdx.x >> 6;
    const int b0   = blockIdx.x * NB2;

    float wx[64];
    #pragma unroll
    for (int k = 0; k < 16; ++k) {
        const float4 t4 = *reinterpret_cast<const float4*>(w_x + lane * 256 + sub * 64 + k * 4);
        wx[4*k+0] = t4.x; wx[4*k+1] = t4.y; wx[4*k+2] = t4.z; wx[4*k+3] = t4.w;
    }

    __shared__ float part[4][NB2][64];
    #pragma unroll
    for (int b = 0; b < NB2; b += 2) {
        const float* hb0 = h_new + (size_t)(b0 + b) * 256 + sub * 64;  // wave-uniform
        const float* hb1 = hb0 + 256;
        float a0 = 0.f, a1 = 0.f;
        #pragma unroll
        for (int k = 0; k < 64; ++k) {
            a0 = fmaf(wx[k], hb0[k], a0);
            a1 = fmaf(wx[k], hb1[k], a1);
        }
        part[sub][b][lane]   = a0;
        part[sub][b+1][lane] = a1;
    }
    __syncthreads();

    const float bx = b_x[lane];
    for (int bb = sub; bb < NB2; bb += 4) {
        const float r = part[0][bb][lane] + part[1][bb][lane]
                      + part[2][bb][lane] + part[3][bb][lane] + bx;
        x_out[(size_t)(b0 + bb) * 64 + lane] = r;
    }
}

// ---------------------------------------------------------------------------
extern "C" void kernel_launch(void* const* d_in, const int* in_sizes, int n_in,
                              void* d_out, int out_size, void* d_ws, size_t ws_size,
                              hipStream_t stream)
{
    const float* y    = (const float*)d_in[0];
    const float* H    = (const float*)d_in[1];
    const float* x0   = (const float*)d_in[2];
    const float* h    = (const float*)d_in[3];
    const float* ss   = (const float*)d_in[4];
    const float* Wih  = (const float*)d_in[5];
    const float* Whh  = (const float*)d_in[6];
    const float* bih  = (const float*)d_in[7];
    const float* bhh  = (const float*)d_in[8];
    const float* wx   = (const float*)d_in[9];
    const float* bx   = (const float*)d_in[10];
    const int*   iters= (const int*)d_in[11];

    const int B = in_sizes[0] / 64;                 // 16384 batches
    float* x_out = (float*)d_out;                   // B*64
    float* h_new = (float*)d_out + (size_t)B * 64;  // B*256
    float* z_ws  = (float*)d_ws;                    // B*64 scratch (4 MB)

    gd_solve<<<B / 4,   256, 0, stream>>>(y, H, x0, ss, iters, z_ws);
    rnn_cell<<<B / NB1, 256, 0, stream>>>(z_ws, h, Wih, Whh, bih, bhh, h_new);
    out_proj<<<B / NB2, 256, 0, stream>>>(h_new, wx, bx, x_out);
}